// Round 1
// baseline (265.012 us; speedup 1.0000x reference)
//
#include <hip/hip_runtime.h>
#include <hip/hip_bf16.h>
#include <stdint.h>

typedef __attribute__((ext_vector_type(8))) short bf16x8;
typedef __attribute__((ext_vector_type(4))) float f32x4;

#define NB 16
#define NC 256
#define NHW 4096
#define NK 2304  // 9*256

// ---------- prep: x NCHW f32 -> xt NHWC bf16 (tile transpose) ----------
__global__ __launch_bounds__(256) void prep_xt(const float* __restrict__ x,
                                               __hip_bfloat16* __restrict__ xt) {
  __shared__ float tile[64][65];
  const int b = blockIdx.z;
  const int cb = blockIdx.y << 6;
  const int pb = blockIdx.x << 6;
  const float* xs = x + ((size_t)(b * NC + cb) << 12) + pb;
#pragma unroll
  for (int k = 0; k < 16; ++k) {
    int idx = threadIdx.x + (k << 8);
    int c = idx >> 6, p = idx & 63;
    tile[p][c] = xs[((size_t)c << 12) + p];
  }
  __syncthreads();
  __hip_bfloat16* xd = xt + ((size_t)(b * NHW + pb) << 8) + cb;
#pragma unroll
  for (int k = 0; k < 16; ++k) {
    int idx = threadIdx.x + (k << 8);
    int p = idx >> 6, c = idx & 63;
    xd[(p << 8) + c] = __float2bfloat16(tile[p][c]);
  }
}

// ---------- prep: kernel [b][co][ci][3][3] f32 -> kt [b][co][s][ci] bf16 ----------
__global__ __launch_bounds__(256) void prep_kt(const float* __restrict__ kin,
                                               __hip_bfloat16* __restrict__ kt) {
  const size_t base = (size_t)blockIdx.x * NK;  // blockIdx.x = b*256+co
  const int ci = threadIdx.x;
  float v[9];
#pragma unroll
  for (int s = 0; s < 9; ++s) v[s] = kin[base + ci * 9 + s];
#pragma unroll
  for (int s = 0; s < 9; ++s) kt[base + (s << 8) + ci] = __float2bfloat16(v[s]);
}

// ---------- implicit-GEMM conv, 128x128 tile, BK=32 ----------
// PASS 1: A=image(M=pixel), B=kernel(N=co), out = ht bf16 NHWC (relu)
// PASS 2: A=kernel(M=co), B=image(N=pixel), out = fp32 NCHW (x + .., relu)
template <int PASS>
__global__ __launch_bounds__(256) void conv_gemm(
    const __hip_bfloat16* __restrict__ img,  // [B][4096][256] bf16 (xt or ht)
    const __hip_bfloat16* __restrict__ kt,   // [B][256][2304] bf16
    const float* __restrict__ xres,          // pass2 residual (NCHW f32)
    void* __restrict__ outp) {
  __shared__ short Is[4096];  // 128 pixel-rows x 32 ci (swizzled 16B chunks)
  __shared__ short Ks[4096];  // 128 co-rows    x 32 k

  const int tid = threadIdx.x;
  const int lane = tid & 63;
  const int wid = tid >> 6;
  const int wm = wid >> 1;
  const int wn = wid & 1;

  const int b = blockIdx.z;
  const int pix_tile = (PASS == 1) ? blockIdx.y : blockIdx.x;
  const int co_tile = (PASS == 1) ? blockIdx.x : blockIdx.y;
  const int pbase = pix_tile << 7;
  const int cobase = co_tile << 7;

  // staging: thread t handles tile-row sm (and sm+64), 16B chunk sc
  const int sm = tid >> 2;
  const int sc = tid & 3;
  const int r0 = pix_tile * 2;  // image row of pixels [pbase, pbase+64)
  const int r1 = r0 + 1;

  const __hip_bfloat16* imgb = img + ((size_t)b << 20);
  const __hip_bfloat16* krow0 = kt + (size_t)(b * NC + cobase + sm) * NK;
  const __hip_bfloat16* krow1 = krow0 + (size_t)64 * NK;

  // LDS write offsets (shorts), chunk XOR-swizzled: slot = sc ^ ((row>>1)&3)
  const int w0 = (sm << 5) + (((sc ^ ((sm >> 1) & 3))) << 3);
  const int m1 = sm + 64;
  const int w1 = (m1 << 5) + (((sc ^ ((m1 >> 1) & 3))) << 3);

  // fragment read offsets (shorts): row = wX*64+i*16+(lane&15), chunk = lane>>4
  int aoff[4], boff[4];
#pragma unroll
  for (int i = 0; i < 4; ++i) {
    int ma = (wm << 6) + (i << 4) + (lane & 15);
    aoff[i] = (ma << 5) + ((((lane >> 4) ^ ((ma >> 1) & 3))) << 3);
    int nb = (wn << 6) + (i << 4) + (lane & 15);
    boff[i] = (nb << 5) + ((((lane >> 4) ^ ((nb >> 1) & 3))) << 3);
  }

  const short* At = (PASS == 1) ? Is : Ks;
  const short* Bt = (PASS == 1) ? Ks : Is;

  f32x4 acc[4][4];
#pragma unroll
  for (int i = 0; i < 4; ++i)
#pragma unroll
    for (int j = 0; j < 4; ++j) acc[i][j] = (f32x4){0.f, 0.f, 0.f, 0.f};

  uint4 cimg0, cimg1, cker0, cker1;

  auto load_step = [&](int step, uint4& vi0, uint4& vi1, uint4& vk0, uint4& vk1) {
    const int s = step >> 3;              // 0..8 = (kh,kw)
    const int ci0 = (step & 7) << 5;      // ci block
    const int dh = s / 3 - 1;
    const int dw = s % 3 - 1;
    const int cc = sm + dw;               // shifted column
    const bool okc = (unsigned)cc < 64u;
    const bool ok0 = okc && ((unsigned)(r0 + dh) < 64u);
    const bool ok1 = okc && ((unsigned)(r1 + dh) < 64u);
    const int cio = ci0 + (sc << 3);
    const uint4 z = {0u, 0u, 0u, 0u};
    const int p0 = ((r0 + dh) << 6) + cc;
    const int p1 = ((r1 + dh) << 6) + cc;
    vi0 = ok0 ? *(const uint4*)(imgb + (((size_t)p0) << 8) + cio) : z;
    vi1 = ok1 ? *(const uint4*)(imgb + (((size_t)p1) << 8) + cio) : z;
    const int ko = (s << 8) + cio;
    vk0 = *(const uint4*)(krow0 + ko);
    vk1 = *(const uint4*)(krow1 + ko);
  };

  load_step(0, cimg0, cimg1, cker0, cker1);

#pragma unroll 1
  for (int step = 0; step < 72; ++step) {
    __syncthreads();
    *(uint4*)&Is[w0] = cimg0;
    *(uint4*)&Is[w1] = cimg1;
    *(uint4*)&Ks[w0] = cker0;
    *(uint4*)&Ks[w1] = cker1;
    __syncthreads();
    if (step + 1 < 72) load_step(step + 1, cimg0, cimg1, cker0, cker1);
    bf16x8 fa[4], fb[4];
#pragma unroll
    for (int i = 0; i < 4; ++i) fa[i] = *(const bf16x8*)(At + aoff[i]);
#pragma unroll
    for (int j = 0; j < 4; ++j) fb[j] = *(const bf16x8*)(Bt + boff[j]);
#pragma unroll
    for (int i = 0; i < 4; ++i)
#pragma unroll
      for (int j = 0; j < 4; ++j)
        acc[i][j] = __builtin_amdgcn_mfma_f32_16x16x32_bf16(fa[i], fb[j], acc[i][j], 0, 0, 0);
  }

  const int lg = lane >> 4;
  const int ln = lane & 15;
  if (PASS == 1) {
    __hip_bfloat16* ho = (__hip_bfloat16*)outp;
#pragma unroll
    for (int i = 0; i < 4; ++i)
#pragma unroll
      for (int j = 0; j < 4; ++j)
#pragma unroll
        for (int r = 0; r < 4; ++r) {
          int pixel = pbase + (wm << 6) + (i << 4) + (lg << 2) + r;
          int co = cobase + (wn << 6) + (j << 4) + ln;
          float v = acc[i][j][r];
          v = v > 0.f ? v : 0.f;
          ho[((size_t)(b * NHW + pixel) << 8) + co] = __float2bfloat16(v);
        }
  } else {
    float* oo = (float*)outp;
    (void)xres;
#pragma unroll
    for (int i = 0; i < 4; ++i)
#pragma unroll
      for (int j = 0; j < 4; ++j)
#pragma unroll
        for (int r = 0; r < 4; ++r) {
          int co = cobase + (wm << 6) + (i << 4) + (lg << 2) + r;
          int pixel = pbase + (wn << 6) + (j << 4) + ln;
          size_t idx = ((size_t)(b * NC + co) << 12) + pixel;
          float v = acc[i][j][r] + xres[idx];
          oo[idx] = v > 0.f ? v : 0.f;
        }
  }
}

extern "C" void kernel_launch(void* const* d_in, const int* in_sizes, int n_in,
                              void* d_out, int out_size, void* d_ws, size_t ws_size,
                              hipStream_t stream) {
  const float* x = (const float*)d_in[0];
  const float* k1 = (const float*)d_in[1];
  const float* k2 = (const float*)d_in[2];

  // ws layout: xt (32MB) | ht (32MB) | kt (18MB, reused for k1 then k2)
  __hip_bfloat16* xt = (__hip_bfloat16*)d_ws;
  __hip_bfloat16* ht = xt + (size_t)NB * NHW * NC;
  __hip_bfloat16* kt = ht + (size_t)NB * NHW * NC;

  prep_xt<<<dim3(64, 4, NB), 256, 0, stream>>>(x, xt);
  prep_kt<<<dim3(NB * NC), 256, 0, stream>>>(k1, kt);
  conv_gemm<1><<<dim3(2, 32, NB), 256, 0, stream>>>(xt, kt, nullptr, (void*)ht);
  prep_kt<<<dim3(NB * NC), 256, 0, stream>>>(k2, kt);
  conv_gemm<2><<<dim3(32, 2, NB), 256, 0, stream>>>(ht, kt, x, d_out);
}